// Round 7
// baseline (28116.461 us; speedup 1.0000x reference)
//
#include <hip/hip_runtime.h>
#include <hip/hip_bf16.h>
#include <math.h>

#define BB 256
#define TT 256
#define INW 256
#define HH 1024
#define LL 8
#define CSW 10
#define OUTW 64
#define GG 4112
#define KH 1024            // recurrent K (h only)
#define KXP 896            // x-part GEMM K: 3*288 = 864 padded
#define NPAD 4224          // 4112 padded to 33*128
#define BH (BB * HH)

typedef __attribute__((ext_vector_type(8))) short short8;
typedef __attribute__((ext_vector_type(4))) float f32x4;

__device__ __forceinline__ float bf2f(ushort u) {
    union { float f; unsigned int i; } v; v.i = ((unsigned int)u) << 16; return v.f;
}
__device__ __forceinline__ ushort f2bf(float f) {
    __hip_bfloat16 h = __float2bfloat16(f);
    return *(ushort*)&h;
}
__device__ __forceinline__ float sigf(float v) { return 1.0f / (1.0f + expf(-v)); }

// ---------------- software grid barrier (single-use counters) ----------------
__device__ __forceinline__ void grid_barrier(unsigned int* bar, int idx, int nblk)
{
    __syncthreads();
    if (threadIdx.x == 0) {
        __threadfence();   // release: flush this XCD's L2
        __hip_atomic_fetch_add(&bar[idx], 1u, __ATOMIC_ACQ_REL, __HIP_MEMORY_SCOPE_AGENT);
        while (__hip_atomic_load(&bar[idx], __ATOMIC_RELAXED, __HIP_MEMORY_SCOPE_AGENT) < (unsigned int)nblk)
            __builtin_amdgcn_s_sleep(4);
        __threadfence();   // acquire: invalidate stale lines
    }
    __syncthreads();
}

// ================= persistent scan kernel =================
// grid = 256 blocks x 256 threads. Per step:
//  phase G: 198 GEMM jobs (128m x 128n):
//    p<33 (Whi panel): 4 members = (mt,kh): z0+z2 dual-stream on k-half -> xoP[kh]
//    p>=33 (Wlo panel): 2 members = mt: z1 full-K -> xoP[2]
//  phase S: block b == batch row b: sum partials + xoX + bc, softmax, gates,
//           write hRing(hi) + hLo + c + dist.
__global__ __launch_bounds__(256) void scan_kernel(
    const ushort* __restrict__ WhiT, const ushort* __restrict__ WloT,
    ushort* __restrict__ hR, ushort* __restrict__ hLo, float* __restrict__ cSt,
    const float* __restrict__ xoX, const float* __restrict__ bc,
    float* __restrict__ xoP, float* __restrict__ dist,
    unsigned int* __restrict__ bar, int tBase, int TCH, int RING, int NBLK)
{
    constexpr int LS = 72;
    __shared__ ushort Bs[128 * LS];
    __shared__ ushort Ahs[128 * LS];
    __shared__ ushort Als[128 * LS];
    __shared__ float fmS[LL], imS[LL];

    const int tid = threadIdx.x;
    const int lane = tid & 63, wave = tid >> 6;
    const int wr = wave >> 1, wc = wave & 1;
    const int bid = blockIdx.x;

    // ---- job decode (panel-pinned: panel p served by XCD p%8) ----
    int xcd = bid & 7, q = bid >> 3;
    int p = -1, mem = 0;
    for (int j = 0; ; ++j) {
        int pp = xcd + 8 * j;
        if (pp >= 66) break;
        int cc = (pp < 33) ? 4 : 2;
        if (q < cc) { p = pp; mem = q; break; }
        q -= cc;
    }
    int nt = 0, mt = 0, kBeg = 0, nIter = 0, pout = 0;
    bool dual = false;
    const ushort* Bsrc = WhiT;
    if (p >= 0) {
        if (p < 33) { nt = p;      mt = mem >> 1; kBeg = (mem & 1) * 512; nIter = 8;  pout = mem & 1; dual = true;  Bsrc = WhiT; }
        else        { nt = p - 33; mt = mem;      kBeg = 0;               nIter = 16; pout = 2;       dual = false; Bsrc = WloT; }
    }
    const int m0 = mt * 128, n0 = nt * 128;
    const size_t SPL = (size_t)BB * NPAD;

    for (int tt = 0; tt < TCH; ++tt) {
        const int t = tBase + tt;
        // ================= phase G =================
        if (p >= 0) {
            const ushort* AhiG = hR + (size_t)((t + 8) % RING) * BH;
            f32x4 acc[4][4] = {};
            short8 vB[4], vH[4], vL[4];
            auto gath = [&](int kt) {
#pragma unroll
                for (int i = 0; i < 4; ++i) {
                    int id = tid + i * 256;
                    int r = id >> 3, c8 = id & 7;
                    int k = kBeg + kt + c8 * 8;
                    vB[i] = *(const short8*)(Bsrc + (size_t)(n0 + r) * KH + k);
                    vH[i] = *(const short8*)(AhiG + (size_t)(m0 + r) * HH + k);
                    if (dual) vL[i] = *(const short8*)(hLo + (size_t)(m0 + r) * HH + k);
                }
            };
            gath(0);
            for (int it = 0; it < nIter; ++it) {
#pragma unroll
                for (int i = 0; i < 4; ++i) {
                    int id = tid + i * 256;
                    int r = id >> 3, c8 = id & 7;
                    *(short8*)(Bs + r * LS + c8 * 8) = vB[i];
                    *(short8*)(Ahs + r * LS + c8 * 8) = vH[i];
                    if (dual) *(short8*)(Als + r * LS + c8 * 8) = vL[i];
                }
                __syncthreads();
                if (it + 1 < nIter) gath((it + 1) * 64);
#pragma unroll
                for (int kf = 0; kf < 2; ++kf) {
                    short8 aH[4], bF[4];
#pragma unroll
                    for (int mi = 0; mi < 4; ++mi)
                        aH[mi] = *(const short8*)(Ahs + (wr * 64 + mi * 16 + (lane & 15)) * LS + kf * 32 + (lane >> 4) * 8);
#pragma unroll
                    for (int ni = 0; ni < 4; ++ni)
                        bF[ni] = *(const short8*)(Bs + (wc * 64 + ni * 16 + (lane & 15)) * LS + kf * 32 + (lane >> 4) * 8);
#pragma unroll
                    for (int mi = 0; mi < 4; ++mi)
#pragma unroll
                        for (int ni = 0; ni < 4; ++ni)
                            acc[mi][ni] = __builtin_amdgcn_mfma_f32_16x16x32_bf16(aH[mi], bF[ni], acc[mi][ni], 0, 0, 0);
                    if (dual) {
                        short8 aL[4];
#pragma unroll
                        for (int mi = 0; mi < 4; ++mi)
                            aL[mi] = *(const short8*)(Als + (wr * 64 + mi * 16 + (lane & 15)) * LS + kf * 32 + (lane >> 4) * 8);
#pragma unroll
                        for (int mi = 0; mi < 4; ++mi)
#pragma unroll
                            for (int ni = 0; ni < 4; ++ni)
                                acc[mi][ni] = __builtin_amdgcn_mfma_f32_16x16x32_bf16(aL[mi], bF[ni], acc[mi][ni], 0, 0, 0);
                    }
                }
                __syncthreads();
            }
            float* dst = xoP + (size_t)pout * SPL;
#pragma unroll
            for (int mi = 0; mi < 4; ++mi)
#pragma unroll
                for (int ni = 0; ni < 4; ++ni)
#pragma unroll
                    for (int j = 0; j < 4; ++j) {
                        int row = m0 + wr * 64 + mi * 16 + ((lane >> 4) << 2) + j;
                        int col = n0 + wc * 64 + ni * 16 + (lane & 15);
                        dst[(size_t)row * NPAD + col] = acc[mi][ni][j];
                    }
        }
        grid_barrier(bar, 2 * tt, NBLK);
        // ================= phase S =================
        if (bid < BB) {
            int b = bid;
            const float* p0 = xoP + (size_t)b * NPAD;
            const float* p1 = p0 + SPL;
            const float* p2 = p1 + SPL;
            const float* xx = xoX + ((size_t)tt * 256 + b) * NPAD;
            if (tid == 0) {
                float xr[2 * LL];
                for (int l = 0; l < 2 * LL; ++l)
                    xr[l] = p0[l] + p1[l] + p2[l] + xx[l] + bc[l];
                float m1 = -1e30f, m2 = -1e30f;
                for (int l = 0; l < LL; ++l) { m1 = fmaxf(m1, xr[l]); m2 = fmaxf(m2, xr[LL + l]); }
                float e1[LL], e2[LL], s1 = 0.f, s2 = 0.f;
                for (int l = 0; l < LL; ++l) {
                    e1[l] = expf(xr[l] - m1); s1 += e1[l];
                    e2[l] = expf(xr[LL + l] - m2); s2 += e2[l];
                }
                float cum = 0.f, mean = 0.f;
                for (int l = 0; l < LL; ++l) { cum += e1[l] / s1; fmS[l] = cum; mean += cum; }
                float rc = 0.f;
                for (int l = LL - 1; l >= 0; --l) { rc += e2[l] / s2; imS[l] = rc; }
                dist[(size_t)t * BB + b] = 1.0f - mean / LL;
            }
            __syncthreads();
            int slot = (t + 9) % RING;
            for (int e = tid; e < HH; e += 256) {
                int l = e >> 7;
                int c0 = 2 * LL + e;
                float f  = sigf(p0[c0] + p1[c0] + p2[c0] + xx[c0] + bc[c0]);
                int c1 = c0 + HH;
                float ig = sigf(p0[c1] + p1[c1] + p2[c1] + xx[c1] + bc[c1]);
                int c2 = c1 + HH;
                float og = sigf(p0[c2] + p1[c2] + p2[c2] + xx[c2] + bc[c2]);
                int c3 = c2 + HH;
                float ci = tanhf(p0[c3] + p1[c3] + p2[c3] + xx[c3] + bc[c3]);
                size_t idx = (size_t)b * HH + e;
                float cl = cSt[idx];
                float F = fmS[l], I = imS[l], OV = F * I;
                float cn = OV * (f * cl + ig * ci) + (F - OV) * cl + (I - OV) * ci;
                float hn = og * tanhf(cn);
                cSt[idx] = cn;
                ushort hi = f2bf(hn);
                hR[(size_t)slot * BH + idx] = hi;
                hLo[idx] = f2bf(hn - bf2f(hi));
            }
        }
        grid_barrier(bar, 2 * tt + 1, NBLK);
    }
}

// ================= generic bf16 MFMA GEMM (phase 2) =================
// AMODE 0: plain bf16 A (rows contiguous at ldaA)
// AMODE 2: conv gather: A[m][k=ks*1024+c] = hR[(tBase+tt+ks)%RING][b][c]*ldw[m][ks]
//          1-D m-tile-pinned grid: bx=(vid>>3)&7, mtile=(vid>>6)*8+(vid&7), nM in `t`
// EPI 0: fp32 store  1: relu->bf16  2: sigmoid->bf16  3: rnn=TH*(v+bias)+h_t->bf16
// EPI 4: out[b][tBase+tt][col] = sigmoid(v+bias) fp32
template<int WR, int WC, int AMODE, int EPI>
__global__ __launch_bounds__(WR * WC * 64) void mm_kernel(
    const ushort* __restrict__ A, const ushort* __restrict__ hR,
    const ushort* __restrict__ hLo,
    const ushort* __restrict__ BT, const float* __restrict__ bias,
    void* __restrict__ Cp, const float* __restrict__ ldw,
    const ushort* __restrict__ TH, float* __restrict__ outp,
    int splitStride, int ldaA, int ldb, int ldc, int K, int t, int RING, int tBase)
{
    constexpr int BM = WR * 64, BN = WC * 64, NT = WR * WC * 64, LS = 72;
    constexpr int AIT = BM * 8 / NT, BIT = BN * 8 / NT;
    __shared__ ushort As[BM * LS];
    __shared__ ushort Bs[BN * LS];
    const int tid = threadIdx.x;
    const int lane = tid & 63, wave = tid >> 6;
    const int wr = wave / WC, wc = wave % WC;

    int bx, by;
    if (AMODE == 2) {
        int vid = blockIdx.x;
        bx = (vid >> 3) & 7;
        by = ((vid >> 6) << 3) + (vid & 7);
        if (by >= t) return;        // t carries nM
    } else {
        bx = blockIdx.x; by = blockIdx.y;
    }
    const int m0 = by * BM, n0 = bx * BN;
    f32x4 acc[4][4] = {};

    auto gather = [&](int ktl, short8* vA, short8* vB) {
#pragma unroll
        for (int i = 0; i < AIT; ++i) {
            int id = tid + i * NT;
            int r = id >> 3, cc = id & 7;
            int k = ktl + cc * 8;
            short8 v;
            if (AMODE == 0) {
                v = *(const short8*)(A + (size_t)(m0 + r) * ldaA + k);
            } else {  // conv gather
                int ks = k >> 10, c = k & 1023;
                int tt = m0 >> 8, b = (m0 & 255) + r;
                int slot = (tBase + tt + ks) % RING;
                short8 hv = *(const short8*)(hR + (size_t)slot * BH + (size_t)b * HH + c);
                float s = ldw[((size_t)tt * 256 + b) * CSW + ks];
                ushort* pv = (ushort*)&hv;
                ushort* po = (ushort*)&v;
#pragma unroll
                for (int j = 0; j < 8; ++j) po[j] = f2bf(bf2f(pv[j]) * s);
            }
            vA[i] = v;
        }
#pragma unroll
        for (int i = 0; i < BIT; ++i) {
            int id = tid + i * NT;
            int n = id >> 3, cc = id & 7;
            vB[i] = *(const short8*)(BT + (size_t)(n0 + n) * ldb + ktl + cc * 8);
        }
    };

    short8 vA[AIT], vB[BIT];
    gather(0, vA, vB);

    for (int kt = 0; kt < K; kt += 64) {
#pragma unroll
        for (int i = 0; i < AIT; ++i) {
            int id = tid + i * NT;
            *(short8*)(As + (id >> 3) * LS + (id & 7) * 8) = vA[i];
        }
#pragma unroll
        for (int i = 0; i < BIT; ++i) {
            int id = tid + i * NT;
            *(short8*)(Bs + (id >> 3) * LS + (id & 7) * 8) = vB[i];
        }
        __syncthreads();
        if (kt + 64 < K) gather(kt + 64, vA, vB);
#pragma unroll
        for (int kf = 0; kf < 2; ++kf) {
            short8 aF[4], bF[4];
#pragma unroll
            for (int mi = 0; mi < 4; ++mi)
                aF[mi] = *(const short8*)(As + (wr * 64 + mi * 16 + (lane & 15)) * LS + kf * 32 + (lane >> 4) * 8);
#pragma unroll
            for (int ni = 0; ni < 4; ++ni)
                bF[ni] = *(const short8*)(Bs + (wc * 64 + ni * 16 + (lane & 15)) * LS + kf * 32 + (lane >> 4) * 8);
#pragma unroll
            for (int mi = 0; mi < 4; ++mi)
#pragma unroll
                for (int ni = 0; ni < 4; ++ni)
                    acc[mi][ni] = __builtin_amdgcn_mfma_f32_16x16x32_bf16(aF[mi], bF[ni], acc[mi][ni], 0, 0, 0);
        }
        __syncthreads();
    }
#pragma unroll
    for (int mi = 0; mi < 4; ++mi) {
#pragma unroll
        for (int ni = 0; ni < 4; ++ni) {
#pragma unroll
            for (int j = 0; j < 4; ++j) {
                int row = m0 + wr * 64 + mi * 16 + ((lane >> 4) << 2) + j;
                int col = n0 + wc * 64 + ni * 16 + (lane & 15);
                float v = acc[mi][ni][j];
                if (EPI != 0 && bias) v += bias[col];
                if (EPI == 0) {
                    ((float*)Cp)[(size_t)row * ldc + col] = v;
                } else if (EPI == 1) {
                    ((ushort*)Cp)[(size_t)row * ldc + col] = f2bf(v > 0.f ? v : 0.f);
                } else if (EPI == 2) {
                    ((ushort*)Cp)[(size_t)row * ldc + col] = f2bf(sigf(v));
                } else if (EPI == 3) {
                    int tt = row >> 8, b = row & 255;
                    int slot = (tBase + tt + 9) % RING;
                    float th = bf2f(TH[(size_t)row * HH + col]);
                    float h  = bf2f(hR[(size_t)slot * BH + (size_t)b * HH + col]);
                    ((ushort*)Cp)[(size_t)row * ldc + col] = f2bf(th * v + h);
                } else {
                    int tt = tBase + (row >> 8), b = row & 255;
                    outp[((size_t)b * TT + tt) * OUTW + col] = sigf(v);
                }
            }
        }
    }
}

// ================= weight / input prep =================
__global__ void build_whl(const float* __restrict__ rw,
                          ushort* __restrict__ WhiT, ushort* __restrict__ WloT)
{
    size_t i = (size_t)blockIdx.x * 256 + threadIdx.x;
    if (i >= (size_t)NPAD * KH) return;
    int n = (int)(i / KH), k = (int)(i % KH);
    float w = (n < GG) ? rw[(size_t)k * GG + n] : 0.f;
    ushort hi = f2bf(w);
    WhiT[i] = hi;
    WloT[i] = f2bf(w - bf2f(hi));
}

__global__ void build_wxt(const float* __restrict__ kw, const float* __restrict__ rw,
                          ushort* __restrict__ WxT)
{
    size_t i = (size_t)blockIdx.x * 256 + threadIdx.x;
    if (i >= (size_t)NPAD * KXP) return;
    int n = (int)(i / KXP), k = (int)(i % KXP);
    int seg = k / 288, kk = k - seg * 288;
    float w = 0.f;
    if (n < GG && seg < 3) {
        if (kk < 256)       w = kw[(size_t)kk * GG + n];
        else if (kk == 256) w = kw[(size_t)256 * GG + n];
        else if (kk == 257) w = rw[(size_t)1024 * GG + n];
    }
    ushort hi = f2bf(w);
    WxT[i] = (seg == 1) ? f2bf(w - bf2f(hi)) : hi;
}

__global__ void build_bc(const float* __restrict__ kb, const float* __restrict__ rb,
                         float* __restrict__ bc)
{
    int i = blockIdx.x * 256 + threadIdx.x;
    if (i < NPAD) bc[i] = (i < GG) ? kb[i] + rb[i] : 0.f;
}

__global__ void build_xac(const float* __restrict__ x, const float* __restrict__ tim,
                          ushort* __restrict__ XAc, int tBase, int Mloc)
{
    size_t i = (size_t)blockIdx.x * 256 + threadIdx.x;
    if (i >= (size_t)Mloc * KXP) return;
    int m = (int)(i / KXP), k = (int)(i % KXP);
    int t = tBase + (m >> 8), b = m & 255;
    int seg = k / 288, kk = k - seg * 288;
    float v = 0.f;
    if (seg < 3) {
        if (kk < 256)       v = x[((size_t)b * TT + t) * INW + kk];
        else if (kk < 258)  v = tim[(size_t)b * TT + t];
    }
    ushort hi = f2bf(v);
    XAc[i] = (seg == 2) ? f2bf(v - bf2f(hi)) : hi;
}

__global__ void build_ctt(const float* __restrict__ cw, ushort* __restrict__ ctT)
{
    size_t i = (size_t)blockIdx.x * 256 + threadIdx.x;
    if (i >= (size_t)HH * HH * CSW) return;
    int o = (int)(i / (HH * CSW)), rest = (int)(i % (HH * CSW));
    int k = rest >> 10, c = rest & 1023;
    ctT[i] = f2bf(cw[((size_t)o * HH + c) * CSW + k]);
}

__global__ void build_swt(const float* __restrict__ sw, const float* __restrict__ sb,
                          ushort* __restrict__ swT, float* __restrict__ sbP)
{
    int i = blockIdx.x * 256 + threadIdx.x;
    if (i < 256 * 1024) {
        int n = i >> 10, k = i & 1023;
        swT[i] = f2bf(n < 170 ? sw[(size_t)k * 170 + n] : 0.f);
    }
    if (i < 256) sbP[i] = (i < 170) ? sb[i] : 0.f;
}

__global__ void build_rswt(const float* __restrict__ rsw, ushort* __restrict__ rswT)
{
    int i = blockIdx.x * 256 + threadIdx.x;
    if (i >= 1024 * 256) return;
    int n = i >> 8, k = i & 255;
    rswT[i] = f2bf(k < 170 ? rsw[(size_t)k * HH + n] : 0.f);
}

__global__ void build_owt(const float* __restrict__ ow, ushort* __restrict__ owT)
{
    int i = blockIdx.x * 256 + threadIdx.x;
    if (i >= OUTW * HH) return;
    int n = i >> 10, k = i & 1023;
    owT[i] = f2bf(ow[(size_t)k * OUTW + n]);
}

// ================= chunk helpers =================
__global__ void ld_chunk_kernel(const float* __restrict__ dist, float* __restrict__ ldC,
                                int tBase, int Mloc)
{
    int id = blockIdx.x * 256 + threadIdx.x;
    if (id >= Mloc) return;
    int t = tBase + (id >> 8), b = id & 255;
    float cv[CSW], cum = 0.f, mx = -1e30f;
#pragma unroll
    for (int k = 0; k < CSW; ++k) {
        int ts = t - 9 + k;
        cum += (ts >= 0) ? dist[(size_t)ts * BB + b] : 0.f;
        cv[k] = cum; mx = fmaxf(mx, cum);
    }
    float ss = 0.f;
#pragma unroll
    for (int k = 0; k < CSW; ++k) { cv[k] = expf(cv[k] - mx); ss += cv[k]; }
    float inv = 1.0f / ss;
#pragma unroll
    for (int k = 0; k < CSW; ++k) ldC[(size_t)id * CSW + k] = cv[k] * inv;
}

__global__ void mlh_kernel(const ushort* __restrict__ hR, const float* __restrict__ ldC,
                           ushort* __restrict__ MLH, int tBase, int RING)
{
    size_t id = (size_t)blockIdx.x * 256 + threadIdx.x;
    int m = (int)(id >> 7);
    int c0 = ((int)(id & 127)) << 3;
    int t = tBase + (m >> 8), b = m & 255;
    float acc[8] = {};
#pragma unroll
    for (int k = 0; k < CSW; ++k) {
        float s = ldC[(size_t)m * CSW + k];
        int slot = (t + k) % RING;
        short8 hv = *(const short8*)(hR + (size_t)slot * BH + (size_t)b * HH + c0);
        ushort* pv = (ushort*)&hv;
#pragma unroll
        for (int j = 0; j < 8; ++j) acc[j] += bf2f(pv[j]) * s;
    }
#pragma unroll
    for (int j = 0; j < 8; ++j) MLH[(size_t)m * HH + c0 + j] = f2bf(acc[j] * 0.1f);
}

// ================= launch =================
extern "C" void kernel_launch(void* const* d_in, const int* in_sizes, int n_in,
                              void* d_out, int out_size, void* d_ws, size_t ws_size,
                              hipStream_t stream)
{
    const float* x   = (const float*)d_in[0];
    const float* tim = (const float*)d_in[1];
    const float* kw  = (const float*)d_in[2];
    const float* kb  = (const float*)d_in[3];
    const float* rw  = (const float*)d_in[4];
    const float* rb  = (const float*)d_in[5];
    const float* sw  = (const float*)d_in[6];
    const float* sb  = (const float*)d_in[7];
    const float* rsw = (const float*)d_in[8];
    const float* rsb = (const float*)d_in[9];
    const float* cw  = (const float*)d_in[10];
    const float* cb  = (const float*)d_in[11];
    const float* ow  = (const float*)d_in[12];
    const float* ob  = (const float*)d_in[13];
    float* out  = (float*)d_out;
    float* dist = out + (size_t)BB * TT * OUTW;

    auto planSize = [&](int tch) -> size_t {
        size_t o = 0;
        auto al = [&](size_t bytes) { o += (bytes + 255) & ~(size_t)255; };
        int ring = tch + 9;
        al((size_t)ring * BH * 2);             // hRing
        al((size_t)BH * 2);                    // hLo
        al((size_t)BH * 4);                    // c
        al((size_t)NPAD * KH * 2);             // WhiT
        al((size_t)NPAD * KH * 2);             // WloT
        al((size_t)NPAD * KXP * 2);            // WxT
        al((size_t)NPAD * 4);                  // bc
        al((size_t)3 * BB * NPAD * 4);         // xoP
        al((size_t)tch * 256 * NPAD * 4);      // xo_x
        al((size_t)tch * 256 * KXP * 2);       // XAc
        al((size_t)tch * 256 * CSW * 4);       // ldC
        al((size_t)HH * HH * CSW * 2);         // ctT
        al((size_t)256 * 1024 * 2);            // swT
        al((size_t)256 * 4);                   // sbP
        al((size_t)1024 * 256 * 2);            // rswT
        al((size_t)OUTW * HH * 2);             // owT
        al((size_t)tch * 256 * HH * 2);        // MLH / RNN
        al((size_t)tch * 256 * 256 * 2);       // TH1
        al((size_t)tch * 256 * HH * 2);        // TH
        al(1024);                              // barrier counters
        return o;
    };
    const int cands[5] = {32, 16, 8, 4, 2};
    int TCH = 0;
    for (int ci = 0; ci < 5; ++ci)
        if (planSize(cands[ci]) <= ws_size) { TCH = cands[ci]; break; }
    if (TCH == 0) return;   // diagnostic: output stays zero -> absmax ~0.83
    const int RING = TCH + 9;
    const int Mloc = TCH * 256;
    const int nM = Mloc / 128;
    const int NBLK = 256;

    char* base = (char*)d_ws;
    size_t off = 0;
    auto alloc = [&](size_t bytes) { char* p = base + off; off += (bytes + 255) & ~(size_t)255; return p; };
    ushort* hRing = (ushort*)alloc((size_t)RING * BH * 2);
    ushort* hLo   = (ushort*)alloc((size_t)BH * 2);
    float*  cSt   = (float*) alloc((size_t)BH * 4);
    ushort* WhiT  = (ushort*)alloc((size_t)NPAD * KH * 2);
    ushort* WloT  = (ushort*)alloc((size_t)NPAD * KH * 2);
    ushort* WxT   = (ushort*)alloc((size_t)NPAD * KXP * 2);
    float*  bc    = (float*) alloc((size_t)NPAD * 4);
    float*  xoP   = (float*) alloc((size_t)3 * BB * NPAD * 4);
    float*  xoX   = (float*) alloc((size_t)Mloc * NPAD * 4);
    ushort* XAc   = (ushort*)alloc((size_t)Mloc * KXP * 2);
    float*  ldC   = (float*) alloc((size_t)Mloc * CSW * 4);
    ushort* ctT   = (ushort*)alloc((size_t)HH * HH * CSW * 2);
    ushort* swT   = (ushort*)alloc((size_t)256 * 1024 * 2);
    float*  sbP   = (float*) alloc((size_t)256 * 4);
    ushort* rswT  = (ushort*)alloc((size_t)1024 * 256 * 2);
    ushort* owT   = (ushort*)alloc((size_t)OUTW * HH * 2);
    ushort* MLH   = (ushort*)alloc((size_t)Mloc * HH * 2);
    ushort* TH1   = (ushort*)alloc((size_t)Mloc * 256 * 2);
    ushort* TH    = (ushort*)alloc((size_t)Mloc * HH * 2);
    unsigned int* bar = (unsigned int*)alloc(1024);
    ushort* RNN   = MLH;

    hipMemsetAsync(hRing, 0, (size_t)9 * BH * 2, stream);
    hipMemsetAsync(hLo, 0, (size_t)BH * 2, stream);
    hipMemsetAsync(cSt, 0, (size_t)BH * 4, stream);

    build_whl<<<(int)(((size_t)NPAD * KH + 255) / 256), 256, 0, stream>>>(rw, WhiT, WloT);
    build_wxt<<<(int)(((size_t)NPAD * KXP + 255) / 256), 256, 0, stream>>>(kw, rw, WxT);
    build_bc<<<(NPAD + 255) / 256, 256, 0, stream>>>(kb, rb, bc);
    build_ctt<<<(int)(((size_t)HH * HH * CSW + 255) / 256), 256, 0, stream>>>(cw, ctT);
    build_swt<<<(256 * 1024 + 255) / 256, 256, 0, stream>>>(sw, sb, swT, sbP);
    build_rswt<<<(1024 * 256 + 255) / 256, 256, 0, stream>>>(rsw, rswT);
    build_owt<<<(OUTW * HH + 255) / 256, 256, 0, stream>>>(ow, owT);

    for (int tBase = 0; tBase < TT; tBase += TCH) {
        // ---- batched x-part: xoX = XAc @ WxT ----
        build_xac<<<(int)(((size_t)Mloc * KXP + 255) / 256), 256, 0, stream>>>(
            x, tim, XAc, tBase, Mloc);
        mm_kernel<2, 2, 0, 0><<<dim3(33, Mloc / 128), 256, 0, stream>>>(
            XAc, nullptr, nullptr, WxT, nullptr, xoX, nullptr, nullptr, nullptr,
            0, KXP, KXP, NPAD, KXP, 0, RING, tBase);
        // ---- persistent scan for the chunk ----
        hipMemsetAsync(bar, 0, (size_t)2 * TCH * 4, stream);
        scan_kernel<<<NBLK, 256, 0, stream>>>(
            WhiT, WloT, hRing, hLo, cSt, xoX, bc, xoP, dist, bar,
            tBase, TCH, RING, NBLK);
        // ---- batched phase-2 ----
        ld_chunk_kernel<<<(Mloc + 255) / 256, 256, 0, stream>>>(dist, ldC, tBase, Mloc);
        mlh_kernel<<<Mloc / 2, 256, 0, stream>>>(hRing, ldC, MLH, tBase, RING);
        mm_kernel<2, 2, 0, 1><<<dim3(2, Mloc / 128), 256, 0, stream>>>(
            MLH, nullptr, nullptr, swT, sbP, TH1, nullptr, nullptr, nullptr,
            0, 1024, 1024, 256, 1024, 0, RING, tBase);
        mm_kernel<2, 2, 0, 2><<<dim3(8, Mloc / 128), 256, 0, stream>>>(
            TH1, nullptr, nullptr, rswT, rsb, TH, nullptr, nullptr, nullptr,
            0, 256, 256, 1024, 256, 0, RING, tBase);
        mm_kernel<2, 2, 2, 3><<<dim3(((nM + 7) / 8) * 64), 256, 0, stream>>>(
            nullptr, hRing, nullptr, ctT, cb, RNN, ldC, TH, nullptr,
            0, 0, HH * CSW, 1024, HH * CSW, nM, RING, tBase);
        mm_kernel<4, 1, 0, 4><<<dim3(1, Mloc / 256), 256, 0, stream>>>(
            RNN, nullptr, nullptr, owT, ob, nullptr, nullptr, nullptr, out,
            0, 1024, 1024, 0, 1024, 0, RING, tBase);
    }
}

// Round 8
// 21986.200 us; speedup vs baseline: 1.2788x; 1.2788x over previous
//
#include <hip/hip_runtime.h>
#include <hip/hip_bf16.h>
#include <math.h>

#define BB 256
#define TT 256
#define INW 256
#define HH 1024
#define LL 8
#define CSW 10
#define OUTW 64
#define GG 4112
#define KXP 896            // x-part GEMM K: 3*288 = 864 padded
#define NPAD 4224          // 4112 padded to 33*128
#define BH2 (BB * 2048)    // h ring slot stride: [b][0..1023]=hi, [1024..2047]=lo
#define NBLK 256

typedef __attribute__((ext_vector_type(8))) short short8;
typedef __attribute__((ext_vector_type(4))) float f32x4;

__device__ __forceinline__ float bf2f(ushort u) {
    union { float f; unsigned int i; } v; v.i = ((unsigned int)u) << 16; return v.f;
}
__device__ __forceinline__ ushort f2bf(float f) {
    __hip_bfloat16 h = __float2bfloat16(f);
    return *(ushort*)&h;
}
__device__ __forceinline__ float sigf(float v) { return 1.0f / (1.0f + expf(-v)); }

// ---- IF-visible write-through stores (do NOT touch L2 state of other data) ----
__device__ __forceinline__ void st_wt_u16(ushort* p, ushort v) {
    asm volatile("global_store_short %0, %1, off sc0 sc1" :: "v"(p), "v"((unsigned int)v) : "memory");
}
__device__ __forceinline__ void st_wt_f32x4(float* p, f32x4 v) {
    asm volatile("global_store_dwordx4 %0, %1, off sc0 sc1" :: "v"(p), "v"(v) : "memory");
}

// ---- fence-free grid barrier: drain own stores, count, poll. No L2 invalidate. ----
__device__ __forceinline__ void gbar(unsigned int* bar, int idx) {
    asm volatile("s_waitcnt vmcnt(0)" ::: "memory");
    __syncthreads();
    if (threadIdx.x == 0) {
        __hip_atomic_fetch_add(&bar[idx], 1u, __ATOMIC_RELAXED, __HIP_MEMORY_SCOPE_AGENT);
        while (__hip_atomic_load(&bar[idx], __ATOMIC_RELAXED, __HIP_MEMORY_SCOPE_AGENT) < NBLK)
            __builtin_amdgcn_s_sleep(8);
    }
    __syncthreads();
}

// ================= persistent scan kernel v2 =================
// 256 blocks x 512 threads. Block (mt,nt): mt=(bid&7)>>2 (128 rows), nt=((bid&7)&3)*32+(bid>>3)
// owns permuted gate cols pc0=nt*32 (8 units), W resident in LDS, c resident in registers.
// Helpers (bid>>3==0, one per XCD): also compute the 16 softmax cols for rows hid*32..+31,
// publish fm/im via write-through.
__global__ __launch_bounds__(512) void scan_kernel(
    const ushort* __restrict__ WhiP, const ushort* __restrict__ WloP,
    const ushort* __restrict__ WspT, ushort* __restrict__ hR,
    float* __restrict__ cSt, const float* __restrict__ xoX,
    const float* __restrict__ bcp, float* __restrict__ fmAll,
    float* __restrict__ dist, unsigned int* __restrict__ bar,
    int tBase, int TCH, int RING)
{
    __shared__ ushort Wh_s[32 * 1032];     // 66048 B
    __shared__ ushort Wl_s[32 * 1032];     // 66048 B
    __shared__ ushort AhAl_s[2 * 128 * 36];// 18432 B (hi | lo), aliased as xo f32 after K-loop
    __shared__ ushort Wsp_s[32 * 72];      // 4608 B, aliased as sp f32 after K-loop
    __shared__ float bc_s[32];

    ushort* Ah_s = AhAl_s;
    ushort* Al_s = AhAl_s + 128 * 36;

    const int tid = threadIdx.x, lane = tid & 63, wave = tid >> 6;
    const int bid = blockIdx.x;
    const int xcd = bid & 7, jj = bid >> 3;
    const int mt = xcd >> 2;
    const int nt = (xcd & 3) * 32 + jj;    // 0..127
    const int m0 = mt * 128;
    const int pc0 = nt * 32;
    const bool isHelper = (jj == 0);
    const int hid = xcd;
    const int wr = wave >> 1, wc = wave & 1;   // wave tile: rows wr*32 (2 frags), cols wc*16

    // ---- load W slice to LDS (once) ----
    for (int i = tid; i < 32 * 128; i += 512) {
        int col = i >> 7, k8 = (i & 127) * 8;
        *(short8*)(Wh_s + col * 1032 + k8) = *(const short8*)(WhiP + (size_t)(pc0 + col) * 1024 + k8);
        *(short8*)(Wl_s + col * 1032 + k8) = *(const short8*)(WloP + (size_t)(pc0 + col) * 1024 + k8);
    }
    if (tid < 32) bc_s[tid] = bcp[pc0 + tid];

    // ---- per-thread cell ownership: rows rloc & rloc+64, unit uu ----
    const int rloc = tid >> 3, uu = tid & 7;
    const int grow = m0 + rloc;
    const int e = nt * 8 + uu;
    const int ll = e >> 7;
    float cReg0 = cSt[(size_t)grow * HH + e];
    float cReg1 = cSt[(size_t)(grow + 64) * HH + e];
    __syncthreads();

    const int arow = tid >> 2, ak8 = (tid & 3) * 8;          // A staging: 128 rows x 32k
    const int spHalf = tid >> 6, spRow = (tid >> 2) & 15, spK8 = (tid & 3) * 8; // tid<128

    for (int tt = 0; tt < TCH; ++tt) {
        const int t = tBase + tt;
        const ushort* hA = hR + (size_t)((t + 8) % RING) * BH2 + (size_t)m0 * 2048;
        f32x4 acc0 = {0.f, 0.f, 0.f, 0.f}, acc1 = {0.f, 0.f, 0.f, 0.f};
        f32x4 accsp = {0.f, 0.f, 0.f, 0.f};
        short8 pH, pL, pS = {};
        pH = *(const short8*)(hA + (size_t)arow * 2048 + ak8);
        pL = *(const short8*)(hA + (size_t)arow * 2048 + 1024 + ak8);
        if (isHelper && tid < 128)
            pS = *(const short8*)(WspT + (size_t)(spHalf * 16 + spRow) * 1024 + spK8);

        for (int it = 0; it < 32; ++it) {
            *(short8*)(Ah_s + arow * 36 + ak8) = pH;
            *(short8*)(Al_s + arow * 36 + ak8) = pL;
            if (isHelper && tid < 128)
                *(short8*)(Wsp_s + (spHalf * 16 + spRow) * 72 + spK8) = pS;
            __syncthreads();
            if (it < 31) {
                int kn = (it + 1) * 32;
                pH = *(const short8*)(hA + (size_t)arow * 2048 + kn + ak8);
                pL = *(const short8*)(hA + (size_t)arow * 2048 + 1024 + kn + ak8);
                if (isHelper && tid < 128)
                    pS = *(const short8*)(WspT + (size_t)(spHalf * 16 + spRow) * 1024 + kn + spK8);
            }
            const int fr = lane & 15, fk = (lane >> 4) * 8;
            short8 bH = *(const short8*)(Wh_s + (wc * 16 + fr) * 1032 + it * 32 + fk);
            short8 bL = *(const short8*)(Wl_s + (wc * 16 + fr) * 1032 + it * 32 + fk);
            short8 aH0 = *(const short8*)(Ah_s + (wr * 32 + fr) * 36 + fk);
            short8 aL0 = *(const short8*)(Al_s + (wr * 32 + fr) * 36 + fk);
            short8 aH1 = *(const short8*)(Ah_s + (wr * 32 + 16 + fr) * 36 + fk);
            short8 aL1 = *(const short8*)(Al_s + (wr * 32 + 16 + fr) * 36 + fk);
            acc0 = __builtin_amdgcn_mfma_f32_16x16x32_bf16(aH0, bH, acc0, 0, 0, 0);
            acc0 = __builtin_amdgcn_mfma_f32_16x16x32_bf16(aH0, bL, acc0, 0, 0, 0);
            acc0 = __builtin_amdgcn_mfma_f32_16x16x32_bf16(aL0, bH, acc0, 0, 0, 0);
            acc1 = __builtin_amdgcn_mfma_f32_16x16x32_bf16(aH1, bH, acc1, 0, 0, 0);
            acc1 = __builtin_amdgcn_mfma_f32_16x16x32_bf16(aH1, bL, acc1, 0, 0, 0);
            acc1 = __builtin_amdgcn_mfma_f32_16x16x32_bf16(aL1, bH, acc1, 0, 0, 0);
            if (isHelper && wave < 2) {
                int srl = (hid & 3) * 32 + wave * 16;
                short8 sH = *(const short8*)(Ah_s + (srl + fr) * 36 + fk);
                short8 sL = *(const short8*)(Al_s + (srl + fr) * 36 + fk);
                short8 wH = *(const short8*)(Wsp_s + fr * 72 + fk);
                short8 wL = *(const short8*)(Wsp_s + (16 + fr) * 72 + fk);
                accsp = __builtin_amdgcn_mfma_f32_16x16x32_bf16(sH, wH, accsp, 0, 0, 0);
                accsp = __builtin_amdgcn_mfma_f32_16x16x32_bf16(sH, wL, accsp, 0, 0, 0);
                accsp = __builtin_amdgcn_mfma_f32_16x16x32_bf16(sL, wH, accsp, 0, 0, 0);
            }
            __syncthreads();
        }
        // ---- xo -> LDS (alias A), sp -> LDS (alias Wsp) ----
        float* xo_s = (float*)AhAl_s;   // [128][36]
        float* sp_s = (float*)Wsp_s;    // [32][20] (helpers)
#pragma unroll
        for (int j = 0; j < 4; ++j) {
            int r0 = wr * 32 + ((lane >> 4) << 2) + j;
            int col = wc * 16 + (lane & 15);
            xo_s[r0 * 36 + col] = acc0[j];
            xo_s[(r0 + 16) * 36 + col] = acc1[j];
        }
        if (isHelper && wave < 2) {
#pragma unroll
            for (int j = 0; j < 4; ++j) {
                int srow = wave * 16 + ((lane >> 4) << 2) + j;
                sp_s[srow * 20 + (lane & 15)] = accsp[j];
            }
        }
        __syncthreads();
        // ---- helpers: softmax/cumsum -> fm/im (write-through) + dist ----
        if (isHelper && tid < 32) {
            int r = tid, growS = hid * 32 + r;
            const float* xxs = xoX + ((size_t)tt * 256 + growS) * NPAD + 4096;
            float xr[16];
#pragma unroll
            for (int q = 0; q < 16; ++q) xr[q] = sp_s[r * 20 + q] + xxs[q] + bcp[4096 + q];
            float m1 = -1e30f, m2 = -1e30f;
            for (int q = 0; q < 8; ++q) { m1 = fmaxf(m1, xr[q]); m2 = fmaxf(m2, xr[8 + q]); }
            float e1[8], e2[8], s1 = 0.f, s2 = 0.f;
            for (int q = 0; q < 8; ++q) {
                e1[q] = expf(xr[q] - m1); s1 += e1[q];
                e2[q] = expf(xr[8 + q] - m2); s2 += e2[q];
            }
            float cum = 0.f, mean = 0.f, fmv[8], imv[8];
            for (int q = 0; q < 8; ++q) { cum += e1[q] / s1; fmv[q] = cum; mean += cum; }
            float rc = 0.f;
            for (int q = 7; q >= 0; --q) { rc += e2[q] / s2; imv[q] = rc; }
            float* fp = fmAll + ((size_t)tt * 256 + growS) * 16;
            f32x4 v0 = {fmv[0], fmv[1], fmv[2], fmv[3]}, v1 = {fmv[4], fmv[5], fmv[6], fmv[7]};
            f32x4 v2 = {imv[0], imv[1], imv[2], imv[3]}, v3 = {imv[4], imv[5], imv[6], imv[7]};
            st_wt_f32x4(fp, v0); st_wt_f32x4(fp + 4, v1);
            st_wt_f32x4(fp + 8, v2); st_wt_f32x4(fp + 12, v3);
            dist[(size_t)t * BB + growS] = 1.0f - mean * 0.125f;
        }
        // prefetch x-part for phase S (independent of barrier)
        const float* xxg0 = xoX + ((size_t)tt * 256 + grow) * NPAD + e * 4;
        const float* xxg1 = xoX + ((size_t)tt * 256 + grow + 64) * NPAD + e * 4;
        f32x4 xv0 = *(const f32x4*)xxg0;
        f32x4 xv1 = *(const f32x4*)xxg1;
        gbar(bar, 2 * tt);
        // ---- phase S: gates + cell update, c in registers ----
        {
            float bc0 = bc_s[uu * 4 + 0], bc1 = bc_s[uu * 4 + 1];
            float bc2 = bc_s[uu * 4 + 2], bc3 = bc_s[uu * 4 + 3];
            int slot = (t + 9) % RING;
            // row rloc
            {
                f32x4 g = *(const f32x4*)(xo_s + rloc * 36 + uu * 4);
                float fmv = fmAll[((size_t)tt * 256 + grow) * 16 + ll];
                float imv = fmAll[((size_t)tt * 256 + grow) * 16 + 8 + ll];
                float f = sigf(g[0] + xv0[0] + bc0);
                float ig = sigf(g[1] + xv0[1] + bc1);
                float og = sigf(g[2] + xv0[2] + bc2);
                float ci = tanhf(g[3] + xv0[3] + bc3);
                float OV = fmv * imv;
                float cn = OV * (f * cReg0 + ig * ci) + (fmv - OV) * cReg0 + (imv - OV) * ci;
                float hn = og * tanhf(cn);
                cReg0 = cn;
                ushort hi = f2bf(hn), lo = f2bf(hn - bf2f(hi));
                ushort* hp = hR + (size_t)slot * BH2 + (size_t)grow * 2048 + e;
                st_wt_u16(hp, hi);
                st_wt_u16(hp + 1024, lo);
            }
            // row rloc+64
            {
                f32x4 g = *(const f32x4*)(xo_s + (rloc + 64) * 36 + uu * 4);
                float fmv = fmAll[((size_t)tt * 256 + grow + 64) * 16 + ll];
                float imv = fmAll[((size_t)tt * 256 + grow + 64) * 16 + 8 + ll];
                float f = sigf(g[0] + xv1[0] + bc0);
                float ig = sigf(g[1] + xv1[1] + bc1);
                float og = sigf(g[2] + xv1[2] + bc2);
                float ci = tanhf(g[3] + xv1[3] + bc3);
                float OV = fmv * imv;
                float cn = OV * (f * cReg1 + ig * ci) + (fmv - OV) * cReg1 + (imv - OV) * ci;
                float hn = og * tanhf(cn);
                cReg1 = cn;
                ushort* hp = hR + (size_t)slot * BH2 + (size_t)(grow + 64) * 2048 + e;
                ushort hi = f2bf(hn), lo = f2bf(hn - bf2f(hi));
                st_wt_u16(hp, hi);
                st_wt_u16(hp + 1024, lo);
            }
        }
        gbar(bar, 2 * tt + 1);
    }
    cSt[(size_t)grow * HH + e] = cReg0;
    cSt[(size_t)(grow + 64) * HH + e] = cReg1;
}

// ================= generic bf16 MFMA GEMM (x-part + phase 2) =================
// AMODE 0: plain bf16 A (rows contiguous at ldaA)
// AMODE 2: conv gather: A[m][k=ks*1024+c] = hR[(tBase+tt+ks)%RING][b][hi c]*ldw[m][ks]
//          1-D m-tile-pinned grid; nM passed via t
// EPI 0: fp32 store  1: relu->bf16  2: sigmoid->bf16  3: rnn=TH*(v+bias)+h_t->bf16
// EPI 4: out[b][tBase+tt][col] = sigmoid(v+bias) fp32
template<int WR, int WC, int AMODE, int EPI>
__global__ __launch_bounds__(WR * WC * 64) void mm_kernel(
    const ushort* __restrict__ A, const ushort* __restrict__ hR,
    const ushort* __restrict__ BT, const float* __restrict__ bias,
    void* __restrict__ Cp, const float* __restrict__ ldw,
    const ushort* __restrict__ TH, float* __restrict__ outp,
    int ldaA, int ldb, int ldc, int K, int t, int RING, int tBase)
{
    constexpr int BM = WR * 64, BN = WC * 64, NT = WR * WC * 64, LS = 72;
    constexpr int AIT = BM * 8 / NT, BIT = BN * 8 / NT;
    __shared__ ushort As[BM * LS];
    __shared__ ushort Bs[BN * LS];
    const int tid = threadIdx.x;
    const int lane = tid & 63, wave = tid >> 6;
    const int wr = wave / WC, wc = wave % WC;

    int bx, by;
    if (AMODE == 2) {
        int vid = blockIdx.x;
        bx = (vid >> 3) & 7;
        by = ((vid >> 6) << 3) + (vid & 7);
        if (by >= t) return;        // t carries nM
    } else {
        bx = blockIdx.x; by = blockIdx.y;
    }
    const int m0 = by * BM, n0 = bx * BN;
    f32x4 acc[4][4] = {};

    auto gather = [&](int ktl, short8* vA, short8* vB) {
#pragma unroll
        for (int i = 0; i < AIT; ++i) {
            int id = tid + i * NT;
            int r = id >> 3, cc = id & 7;
            int k = ktl + cc * 8;
            short8 v;
            if (AMODE == 0) {
                v = *(const short8*)(A + (size_t)(m0 + r) * ldaA + k);
            } else {  // conv gather
                int ks = k >> 10, c = k & 1023;
                int tt = m0 >> 8, b = (m0 & 255) + r;
                int slot = (tBase + tt + ks) % RING;
                short8 hv = *(const short8*)(hR + (size_t)slot * BH2 + (size_t)b * 2048 + c);
                float s = ldw[((size_t)tt * 256 + b) * CSW + ks];
                ushort* pv = (ushort*)&hv;
                ushort* po = (ushort*)&v;
#pragma unroll
                for (int j = 0; j < 8; ++j) po[j] = f2bf(bf2f(pv[j]) * s);
            }
            vA[i] = v;
        }
#pragma unroll
        for (int i = 0; i < BIT; ++i) {
            int id = tid + i * NT;
            int n = id >> 3, cc = id & 7;
            vB[i] = *(const short8*)(BT + (size_t)(n0 + n) * ldb + ktl + cc * 8);
        }
    };

    short8 vA[AIT], vB[BIT];
    gather(0, vA, vB);

    for (int kt = 0; kt < K; kt += 64) {
#pragma unroll
        for (int i = 0; i < AIT; ++i) {
            int id = tid + i * NT;
            *(short8*)(As + (id >> 3) * LS + (id & 7) * 8) = vA[i];
        }
#pragma unroll
        for (int i = 0; i < BIT; ++i) {
            int id = tid + i * NT;
            *(short8*)(Bs + (id >> 3) * LS + (id & 7) * 8) = vB[i];
        }
        __syncthreads();
        if (kt + 64 < K) gather(kt + 64, vA, vB);
#pragma unroll
        for (int kf = 0; kf < 2; ++kf) {
            short8 aF[4], bF[4];
#pragma unroll
            for (int mi = 0; mi < 4; ++mi)
                aF[mi] = *(const short8*)(As + (wr * 64 + mi * 16 + (lane & 15)) * LS + kf * 32 + (lane >> 4) * 8);
#pragma unroll
            for (int ni = 0; ni < 4; ++ni)
                bF[ni] = *(const short8*)(Bs + (wc * 64 + ni * 16 + (lane & 15)) * LS + kf * 32 + (lane >> 4) * 8);
#pragma unroll
            for (int mi = 0; mi < 4; ++mi)
#pragma unroll
                for (int ni = 0; ni < 4; ++ni)
                    acc[mi][ni] = __builtin_amdgcn_mfma_f32_16x16x32_bf16(aF[mi], bF[ni], acc[mi][ni], 0, 0, 0);
        }
        __syncthreads();
    }
#pragma unroll
    for (int mi = 0; mi < 4; ++mi) {
#pragma unroll
        for (int ni = 0; ni < 4; ++ni) {
#pragma unroll
            for (int j = 0; j < 4; ++j) {
                int row = m0 + wr * 64 + mi * 16 + ((lane >> 4) << 2) + j;
                int col = n0 + wc * 64 + ni * 16 + (lane & 15);
                float v = acc[mi][ni][j];
                if (EPI != 0 && bias) v += bias[col];
                if (EPI == 0) {
                    ((float*)Cp)[(size_t)row * ldc + col] = v;
                } else if (EPI == 1) {
                    ((ushort*)Cp)[(size_t)row * ldc + col] = f2bf(v > 0.f ? v : 0.f);
                } else if (EPI == 2) {
                    ((ushort*)Cp)[(size_t)row * ldc + col] = f2bf(sigf(v));
                } else if (EPI == 3) {
                    int tt = row >> 8, b = row & 255;
                    int slot = (tBase + tt + 9) % RING;
                    float th = bf2f(TH[(size_t)row * HH + col]);
                    float h = bf2f(hR[(size_t)slot * BH2 + (size_t)b * 2048 + col]);
                    ((ushort*)Cp)[(size_t)row * ldc + col] = f2bf(th * v + h);
                } else {
                    int tt = tBase + (row >> 8), b = row & 255;
                    outp[((size_t)b * TT + tt) * OUTW + col] = sigf(v);
                }
            }
        }
    }
}

// ================= weight / input prep =================
__device__ __forceinline__ int pcol_to_orig(int n) {
    if (n < 4096) return 16 + (n & 3) * 1024 + (n >> 2);
    if (n < 4112) return n - 4096;
    return -1;
}

// permuted gate weights [4096][1024]
__global__ void build_whlP(const float* __restrict__ rw,
                           ushort* __restrict__ WhiP, ushort* __restrict__ WloP)
{
    size_t i = (size_t)blockIdx.x * 256 + threadIdx.x;
    if (i >= (size_t)4096 * 1024) return;
    int pc = (int)(i >> 10), k = (int)(i & 1023);
    int n = 16 + (pc & 3) * 1024 + (pc >> 2);
    float w = rw[(size_t)k * GG + n];
    ushort hi = f2bf(w);
    WhiP[i] = hi;
    WloP[i] = f2bf(w - bf2f(hi));
}

// special softmax cols: [2][16][1024] (hi rows 0..15, lo rows 16..31)
__global__ void build_wsp(const float* __restrict__ rw, ushort* __restrict__ WspT)
{
    int i = blockIdx.x * 256 + threadIdx.x;
    if (i >= 16 * 1024) return;
    int r = i >> 10, k = i & 1023;
    float w = rw[(size_t)k * GG + r];
    ushort hi = f2bf(w);
    WspT[i] = hi;
    WspT[16 * 1024 + i] = f2bf(w - bf2f(hi));
}

// x-part weights, permuted N: WxT[NPAD][KXP]
__global__ void build_wxt(const float* __restrict__ kw, const float* __restrict__ rw,
                          ushort* __restrict__ WxT)
{
    size_t i = (size_t)blockIdx.x * 256 + threadIdx.x;
    if (i >= (size_t)NPAD * KXP) return;
    int n = (int)(i / KXP), k = (int)(i % KXP);
    int seg = k / 288, kk = k - seg * 288;
    int oc = pcol_to_orig(n);
    float w = 0.f;
    if (oc >= 0 && seg < 3) {
        if (kk < 256)       w = kw[(size_t)kk * GG + oc];
        else if (kk == 256) w = kw[(size_t)256 * GG + oc];
        else if (kk == 257) w = rw[(size_t)1024 * GG + oc];
    }
    ushort hi = f2bf(w);
    WxT[i] = (seg == 1) ? f2bf(w - bf2f(hi)) : hi;
}

__global__ void build_bcp(const float* __restrict__ kb, const float* __restrict__ rb,
                          float* __restrict__ bcp)
{
    int i = blockIdx.x * 256 + threadIdx.x;
    if (i >= NPAD) return;
    int oc = pcol_to_orig(i);
    bcp[i] = (oc >= 0) ? kb[oc] + rb[oc] : 0.f;
}

__global__ void build_xac(const float* __restrict__ x, const float* __restrict__ tim,
                          ushort* __restrict__ XAc, int tBase, int Mloc)
{
    size_t i = (size_t)blockIdx.x * 256 + threadIdx.x;
    if (i >= (size_t)Mloc * KXP) return;
    int m = (int)(i / KXP), k = (int)(i % KXP);
    int t = tBase + (m >> 8), b = m & 255;
    int seg = k / 288, kk = k - seg * 288;
    float v = 0.f;
    if (seg < 3) {
        if (kk < 256)      v = x[((size_t)b * TT + t) * INW + kk];
        else if (kk < 258) v = tim[(size_t)b * TT + t];
    }
    ushort hi = f2bf(v);
    XAc[i] = (seg == 2) ? f2bf(v - bf2f(hi)) : hi;
}

__global__ void build_ctt(const float* __restrict__ cw, ushort* __restrict__ ctT)
{
    size_t i = (size_t)blockIdx.x * 256 + threadIdx.x;
    if (i >= (size_t)HH * HH * CSW) return;
    int o = (int)(i / (HH * CSW)), rest = (int)(i % (HH * CSW));
    int k = rest >> 10, c = rest & 1023;
    ctT[i] = f2bf(cw[((size_t)o * HH + c) * CSW + k]);
}

__global__ void build_swt(const float* __restrict__ sw, const float* __restrict__ sb,
                          ushort* __restrict__ swT, float* __restrict__ sbP)
{
    int i = blockIdx.x * 256 + threadIdx.x;
    if (i < 256 * 1024) {
        int n = i >> 10, k = i & 1023;
        swT[i] = f2bf(n < 170 ? sw[(size_t)k * 170 + n] : 0.f);
    }
    if (i < 256) sbP[i] = (i < 170) ? sb[i] : 0.f;
}

__global__ void build_rswt(const float* __restrict__ rsw, ushort* __restrict__ rswT)
{
    int i = blockIdx.x * 256 + threadIdx.x;
    if (i >= 1024 * 256) return;
    int n = i >> 8, k = i & 255;
    rswT[i] = f2bf(k < 170 ? rsw[(size_t)k * HH + n] : 0.f);
}

__global__ void build_owt(const float* __restrict__ ow, ushort* __restrict__ owT)
{
    int i = blockIdx.x * 256 + threadIdx.x;
    if (i >= OUTW * HH) return;
    int n = i >> 10, k = i & 1023;
    owT[i] = f2bf(ow[(size_t)k * OUTW + n]);
}

// ================= chunk helpers =================
__global__ void ld_chunk_kernel(const float* __restrict__ dist, float* __restrict__ ldC,
                                int tBase, int Mloc)
{
    int id = blockIdx.x * 256 + threadIdx.x;
    if (id >= Mloc) return;
    int t = tBase + (id >> 8), b = id & 255;
    float cv[CSW], cum = 0.f, mx = -1e30f;
#pragma unroll
    for (int k = 0; k < CSW; ++k) {
        int ts = t - 9 + k;
        cum += (ts >= 0) ? dist[(size_t)ts * BB + b] : 0.f;
        cv[k] = cum; mx = fmaxf(mx, cum);
    }
    float ss = 0.f;
#pragma unroll
    for (int k = 0; k < CSW; ++k) { cv[k] = expf(cv[k] - mx); ss += cv[k]; }
    float inv = 1.0f / ss;
#pragma unroll
    for (int k = 0; k < CSW; ++k) ldC[(size_t)id * CSW + k] = cv[k] * inv;
}

__global__ void mlh_kernel(const ushort* __restrict__ hR, const float* __restrict__ ldC,
                           ushort* __restrict__ MLH, int tBase, int RING)
{
    size_t id = (size_t)blockIdx.x * 256 + threadIdx.x;
    int m = (int)(id >> 7);
    int c0 = ((int)(id & 127)) << 3;
    int t = tBase + (m >> 8), b = m & 255;
    float acc[8] = {};
#pragma unroll
    for (int k = 0; k < CSW; ++k) {
        float s = ldC[(size_t)m * CSW + k];
        int slot = (t + k) % RING;
        short8 hv = *(const short8*)(hR + (size_t)slot * BH2 + (size_t)b * 2048 + c0);
        ushort* pv = (ushort*)&hv;
#pragma unroll
        for (int j = 0; j < 8; ++j) acc[j] += bf2f(pv[j]) * s;
    }
#pragma unroll
    for (int j = 0; j < 8; ++j) MLH[(size_t)m * HH + c0 + j] = f2bf(acc[j] * 0.1f);
}

// ================= launch =================
extern "C" void kernel_launch(void* const* d_in, const int* in_sizes, int n_in,
                              void* d_out, int out_size, void* d_ws, size_t ws_size,
                              hipStream_t stream)
{
    const float* x   = (const float*)d_in[0];
    const float* tim = (const float*)d_in[1];
    const float* kw  = (const float*)d_in[2];
    const float* kb  = (const float*)d_in[3];
    const float* rw  = (const float*)d_in[4];
    const float* rb  = (const float*)d_in[5];
    const float* sw  = (const float*)d_in[6];
    const float* sb  = (const float*)d_in[7];
    const float* rsw = (const float*)d_in[8];
    const float* rsb = (const float*)d_in[9];
    const float* cw  = (const float*)d_in[10];
    const float* cb  = (const float*)d_in[11];
    const float* ow  = (const float*)d_in[12];
    const float* ob  = (const float*)d_in[13];
    float* out  = (float*)d_out;
    float* dist = out + (size_t)BB * TT * OUTW;

    auto planSize = [&](int tch) -> size_t {
        size_t o = 0;
        auto al = [&](size_t bytes) { o += (bytes + 255) & ~(size_t)255; };
        int ring = tch + 9;
        al((size_t)ring * BH2 * 2);            // hRing (hi|lo)
        al((size_t)BB * HH * 4);               // cSt
        al((size_t)4096 * 1024 * 2);           // WhiP
        al((size_t)4096 * 1024 * 2);           // WloP
        al((size_t)32 * 1024 * 2);             // WspT
        al((size_t)NPAD * KXP * 2);            // WxT
        al((size_t)NPAD * 4);                  // bcp
        al((size_t)tch * 256 * NPAD * 4);      // xoX
        al((size_t)tch * 256 * KXP * 2);       // XAc
        al((size_t)tch * 256 * 16 * 4);        // fmAll
        al((size_t)tch * 256 * CSW * 4);       // ldC
        al((size_t)HH * HH * CSW * 2);         // ctT
        al((size_t)256 * 1024 * 2);            // swT
        al((size_t)256 * 4);                   // sbP
        al((size_t)1024 * 256 * 2);            // rswT
        al((size_t)OUTW * HH * 2);             // owT
        al((size_t)tch * 256 * HH * 2);        // MLH / RNN
        al((size_t)tch * 256 * 256 * 2);       // TH1
        al((size_t)tch * 256 * HH * 2);        // TH
        al(4096);                              // bar
        return o;
    };
    const int cands[4] = {16, 8, 4, 2};
    int TCH = 0;
    for (int ci = 0; ci < 4; ++ci)
        if (planSize(cands[ci]) <= ws_size) { TCH = cands[ci]; break; }
    if (TCH == 0) return;   // diagnostic: output stays zero -> absmax ~0.83
    const int RING = TCH + 9;
    const int Mloc = TCH * 256;
    const int nM = Mloc / 128;

    char* base = (char*)d_ws;
    size_t off = 0;
    auto alloc = [&](size_t bytes) { char* p = base + off; off += (bytes + 255) & ~(size_t)255; return p; };
    ushort* hRing = (ushort*)alloc((size_t)RING * BH2 * 2);
    float*  cSt   = (float*) alloc((size_t)BB * HH * 4);
    ushort* WhiP  = (ushort*)alloc((size_t)4096 * 1024 * 2);
    ushort* WloP  = (ushort*)alloc((size_t)4096 * 1024 * 2);
    ushort* WspT  = (ushort*)alloc((size_t)32 * 1024 * 2);
    ushort* WxT   = (ushort*)alloc((size_t)NPAD * KXP * 2);
    float*  bcp   = (float*) alloc((size_t)NPAD * 4);
    float*  xoX   = (float*) alloc((size_t)Mloc * NPAD * 4);
    ushort* XAc   = (ushort*)alloc((size_t)Mloc * KXP * 2);
    float*  fmAll = (float*) alloc((size_t)Mloc * 16 * 4);
    float*  ldC   = (float*) alloc((size_t)Mloc * CSW * 4);
    ushort* ctT   = (ushort*)alloc((size_t)HH * HH * CSW * 2);
    ushort* swT   = (ushort*)alloc((size_t)256 * 1024 * 2);
    float*  sbP   = (float*) alloc((size_t)256 * 4);
    ushort* rswT  = (ushort*)alloc((size_t)1024 * 256 * 2);
    ushort* owT   = (ushort*)alloc((size_t)OUTW * HH * 2);
    ushort* MLH   = (ushort*)alloc((size_t)Mloc * HH * 2);
    ushort* TH1   = (ushort*)alloc((size_t)Mloc * 256 * 2);
    ushort* TH    = (ushort*)alloc((size_t)Mloc * HH * 2);
    unsigned int* bar = (unsigned int*)alloc(4096);
    ushort* RNN   = MLH;

    hipMemsetAsync(hRing, 0, (size_t)9 * BH2 * 2, stream);
    hipMemsetAsync(cSt, 0, (size_t)BB * HH * 4, stream);

    build_whlP<<<(int)(((size_t)4096 * 1024 + 255) / 256), 256, 0, stream>>>(rw, WhiP, WloP);
    build_wsp<<<(16 * 1024 + 255) / 256, 256, 0, stream>>>(rw, WspT);
    build_wxt<<<(int)(((size_t)NPAD * KXP + 255) / 256), 256, 0, stream>>>(kw, rw, WxT);
    build_bcp<<<(NPAD + 255) / 256, 256, 0, stream>>>(kb, rb, bcp);
    build_ctt<<<(int)(((size_t)HH * HH * CSW + 255) / 256), 256, 0, stream>>>(cw, ctT);
    build_swt<<<(256 * 1024 + 255) / 256, 256, 0, stream>>>(sw, sb, swT, sbP);
    build_rswt<<<(1024 * 256 + 255) / 256, 256, 0, stream>>>(rsw, rswT);
    build_owt<<<(OUTW * HH + 255) / 256, 256, 0, stream>>>(ow, owT);

    for (int tBase = 0; tBase < TT; tBase += TCH) {
        // ---- batched x-part: xoX = XAc @ WxT (permuted N) ----
        build_xac<<<(int)(((size_t)Mloc * KXP + 255) / 256), 256, 0, stream>>>(
            x, tim, XAc, tBase, Mloc);
        mm_kernel<2, 2, 0, 0><<<dim3(33, Mloc / 128), 256, 0, stream>>>(
            XAc, nullptr, WxT, nullptr, xoX, nullptr, nullptr, nullptr,
            KXP, KXP, NPAD, KXP, 0, RING, tBase);
        // ---- persistent scan ----
        hipMemsetAsync(bar, 0, (size_t)2 * TCH * 4, stream);
        scan_kernel<<<NBLK, 512, 0, stream>>>(
            WhiP, WloP, WspT, hRing, cSt, xoX, bcp, fmAll, dist, bar,
            tBase, TCH, RING);
        // ---- batched phase-2 ----
        ld_chunk_kernel<<<(Mloc + 255) / 256, 256, 0, stream>>>(dist, ldC, tBase, Mloc);
        mlh_kernel<<<Mloc / 2, 256, 0, stream>>>(hRing, ldC, MLH, tBase, RING);
        mm_kernel<2, 2, 0, 1><<<dim3(2, Mloc / 128), 256, 0, stream>>>(
            MLH, nullptr, swT, sbP, TH1, nullptr, nullptr, nullptr,
            1024, 1024, 256, 1024, 0, RING, tBase);
        mm_kernel<2, 2, 0, 2><<<dim3(8, Mloc / 128), 256, 0, stream>>>(
            TH1, nullptr, rswT, rsb, TH, nullptr, nullptr, nullptr,
            256, 256, 1024, 256, 0, RING, tBase);
        mm_kernel<2, 2, 2, 3><<<dim3(((nM + 7) / 8) * 64), 256, 0, stream>>>(
            nullptr, hRing, ctT, cb, RNN, ldC, TH, nullptr,
            0, HH * CSW, 1024, HH * CSW, nM, RING, tBase);
        mm_kernel<4, 1, 0, 4><<<dim3(1, Mloc / 256), 256, 0, stream>>>(
            RNN, nullptr, owT, ob, nullptr, nullptr, nullptr, out,
            1024, 1024, 0, 1024, 0, RING, tBase);
    }
}